// Round 2
// baseline (670.787 us; speedup 1.0000x reference)
//
#include <hip/hip_runtime.h>
#include <cstdint>

#define T_DIM 128
#define C_DIM 256
#define HW_DIM 1024
#define B_DIM 16
#define NJR 8       // register j-blocks (64 cols each) in sinkhorn fast path
#define PARTC 640   // max compacted cols handled by fast path

__device__ __forceinline__ float fast_rcp(float x) {
#if defined(__has_builtin)
#if __has_builtin(__builtin_amdgcn_rcpf)
  return __builtin_amdgcn_rcpf(x);
#else
  return 1.0f / x;
#endif
#else
  return 1.0f / x;
#endif
}

// ---------- prep: per-batch fg count + compact position map ----------
__global__ __launch_bounds__(256) void prep_kernel(const int* __restrict__ Ms,
                                                   int* __restrict__ nfg,
                                                   int* __restrict__ pos)
{
  const int b = blockIdx.x, tid = threadIdx.x;
  const int4 m4 = *(const int4*)(Ms + b * HW_DIM + tid * 4);
  const int c = m4.x + m4.y + m4.z + m4.w;
  const int lane = tid & 63, w = tid >> 6;
  int pre = c;
  #pragma unroll
  for (int o = 1; o < 64; o <<= 1) { int t = __shfl_up(pre, (unsigned)o); if (lane >= o) pre += t; }
  __shared__ int wtot[4];
  if (lane == 63) wtot[w] = pre;
  __syncthreads();
  int base = 0;
  #pragma unroll
  for (int i = 0; i < 4; i++) if (i < w) base += wtot[i];
  const int excl = base + pre - c;
  if (tid == 0) nfg[b] = wtot[0] + wtot[1] + wtot[2] + wtot[3];
  int p = excl;
  const int mm[4] = {m4.x, m4.y, m4.z, m4.w};
  #pragma unroll
  for (int q = 0; q < 4; q++) {
    pos[b * HW_DIM + tid * 4 + q] = mm[q] ? p : -1;
    p += mm[q];
  }
}

// ---------- bias-fold vectors: w0 = b_aQ@W_sK^T, wq = W_aQ@b_sK, s0 = b_aQ.b_sK ----------
__global__ __launch_bounds__(256) void wvec_kernel(
    const float* __restrict__ W_aQ, const float* __restrict__ b_aQ,
    const float* __restrict__ W_sK, const float* __restrict__ b_sK,
    float* __restrict__ w0, float* __restrict__ wq, float* __restrict__ s0)
{
  const int wid = blockIdx.x * 4 + (threadIdx.x >> 6);
  const int lane = threadIdx.x & 63;
  if (wid > 512) return;
  float acc = 0.f;
  if (wid < 256) {
    #pragma unroll 4
    for (int j = 0; j < 16; j++) { int h = lane + 64 * j; acc = fmaf(b_aQ[h], W_sK[(size_t)wid * 1024 + h], acc); }
  } else if (wid < 512) {
    const int c = wid - 256;
    #pragma unroll 4
    for (int j = 0; j < 16; j++) { int h = lane + 64 * j; acc = fmaf(W_aQ[(size_t)c * 1024 + h], b_sK[h], acc); }
  } else {
    #pragma unroll 4
    for (int j = 0; j < 16; j++) { int h = lane + 64 * j; acc = fmaf(b_aQ[h], b_sK[h], acc); }
  }
  #pragma unroll
  for (int o = 32; o; o >>= 1) acc += __shfl_xor(acc, o);
  if (lane == 0) {
    if (wid < 256) w0[wid] = acc;
    else if (wid < 512) wq[wid - 256] = acc;
    else s0[0] = acc;
  }
}

// ---------- qb[r] = F_a[r,:].wq + s0 ----------
__global__ __launch_bounds__(256) void qb_kernel(const float* __restrict__ F_a,
    const float* __restrict__ wq, const float* __restrict__ s0, float* __restrict__ qb)
{
  const int r = blockIdx.x * 4 + (threadIdx.x >> 6);
  const int lane = threadIdx.x & 63;
  float acc = 0.f;
  #pragma unroll
  for (int j = 0; j < 4; j++) { int c = lane + 64 * j; acc = fmaf(F_a[(size_t)r * 256 + c], wq[c], acc); }
  #pragma unroll
  for (int o = 32; o; o >>= 1) acc += __shfl_xor(acc, o);
  if (lane == 0) qb[r] = acc + s0[0];
}

// ---------- generic 64x64 tiled fp32 GEMM: C = A * (BT ? B^T : B) + bias ----------
// A[M,K] row-major. BT: B[N,K] row-major; else B[K,N] row-major.
// BIAS: 0 none, 1 col-vector*bscale, 2 per-row scalar (bias[sBias*bz + m]).
template<bool BT, bool RELU, int BIAS>
__global__ __launch_bounds__(256) void gemm_kernel(
    const float* __restrict__ A, int lda, long long sA,
    const float* __restrict__ B, int ldb, long long sB,
    float* __restrict__ C, int ldc, long long sC,
    int M, int N, int K,
    const float* __restrict__ bias, int sBias, float bscale)
{
  __shared__ float As[16][68];
  __shared__ float Bs[16][68];
  const int bz = blockIdx.z;
  A += (size_t)sA * bz;  B += (size_t)sB * bz;  C += (size_t)sC * bz;
  const int m0 = blockIdx.y * 64, n0 = blockIdx.x * 64;
  const int tid = threadIdx.x;
  const int tx = tid & 15, ty = tid >> 4;
  const int lrow = tid >> 2, lk = (tid & 3) * 4;
  const int brow = tid >> 4, bcol = (tid & 15) * 4;
  float acc[4][4];
  #pragma unroll
  for (int i = 0; i < 4; i++)
    #pragma unroll
    for (int j = 0; j < 4; j++) acc[i][j] = 0.f;

  for (int k0 = 0; k0 < K; k0 += 16) {
    const float4 av = *(const float4*)(A + (size_t)(m0 + lrow) * lda + (k0 + lk));
    As[lk + 0][lrow] = av.x; As[lk + 1][lrow] = av.y;
    As[lk + 2][lrow] = av.z; As[lk + 3][lrow] = av.w;
    if (BT) {
      const float4 bv = *(const float4*)(B + (size_t)(n0 + lrow) * ldb + (k0 + lk));
      Bs[lk + 0][lrow] = bv.x; Bs[lk + 1][lrow] = bv.y;
      Bs[lk + 2][lrow] = bv.z; Bs[lk + 3][lrow] = bv.w;
    } else {
      const float4 bv = *(const float4*)(B + (size_t)(k0 + brow) * ldb + (n0 + bcol));
      *(float4*)&Bs[brow][bcol] = bv;
    }
    __syncthreads();
    #pragma unroll
    for (int kk = 0; kk < 16; ++kk) {
      const float4 a4 = *(const float4*)&As[kk][ty * 4];
      const float4 b4 = *(const float4*)&Bs[kk][tx * 4];
      const float ar[4] = {a4.x, a4.y, a4.z, a4.w};
      const float br[4] = {b4.x, b4.y, b4.z, b4.w};
      #pragma unroll
      for (int i = 0; i < 4; i++)
        #pragma unroll
        for (int j = 0; j < 4; j++)
          acc[i][j] = fmaf(ar[i], br[j], acc[i][j]);
    }
    __syncthreads();
  }
  #pragma unroll
  for (int i = 0; i < 4; i++) {
    const int m = m0 + ty * 4 + i;
    float rowb = 0.f;
    if (BIAS == 2) rowb = bias[(size_t)sBias * bz + m];
    float vtmp[4];
    #pragma unroll
    for (int j = 0; j < 4; j++) {
      float val = acc[i][j];
      if (BIAS == 1) val += bscale * bias[n0 + tx * 4 + j];
      if (BIAS == 2) val += rowb;
      if (RELU) val = fmaxf(val, 0.f);
      vtmp[j] = val;
    }
    float4 o4; o4.x = vtmp[0]; o4.y = vtmp[1]; o4.z = vtmp[2]; o4.w = vtmp[3];
    *(float4*)(C + (size_t)m * ldc + (n0 + tx * 4)) = o4;
  }
}

// ---------- row softmax (masked) + Kmat = exp(10*(S-1)); writes full + compacted ----------
__global__ __launch_bounds__(256) void softmax_kernel(
    const float* __restrict__ QK, const int* __restrict__ Ms,
    const int* __restrict__ pos, float* __restrict__ Km, float* __restrict__ Kc)
{
  const int r = blockIdx.x;          // 0..2047 (b*128+t)
  const int b = r >> 7;
  const int tid = threadIdx.x;
  const float4 x = *(const float4*)(QK + (size_t)r * HW_DIM + tid * 4);
  const int4 m4 = *(const int4*)(Ms + b * HW_DIM + tid * 4);
  float mx = -3.0e38f;
  if (m4.x) mx = x.x;
  if (m4.y) mx = fmaxf(mx, x.y);
  if (m4.z) mx = fmaxf(mx, x.z);
  if (m4.w) mx = fmaxf(mx, x.w);
  #pragma unroll
  for (int o = 32; o; o >>= 1) mx = fmaxf(mx, __shfl_xor(mx, o));
  __shared__ float red[4];
  const int lane = tid & 63, w = tid >> 6;
  if (lane == 0) red[w] = mx;
  __syncthreads();
  const float gmax = fmaxf(fmaxf(red[0], red[1]), fmaxf(red[2], red[3]));
  __syncthreads();
  const float e0 = m4.x ? __expf(x.x - gmax) : 0.f;
  const float e1 = m4.y ? __expf(x.y - gmax) : 0.f;
  const float e2 = m4.z ? __expf(x.z - gmax) : 0.f;
  const float e3 = m4.w ? __expf(x.w - gmax) : 0.f;
  float s = e0 + e1 + e2 + e3;
  #pragma unroll
  for (int o = 32; o; o >>= 1) s += __shfl_xor(s, o);
  if (lane == 0) red[w] = s;
  __syncthreads();
  const float inv = 1.0f / (red[0] + red[1] + red[2] + red[3]);
  float4 o4;
  o4.x = __expf(fmaf(10.f, e0 * inv, -10.f));
  o4.y = __expf(fmaf(10.f, e1 * inv, -10.f));
  o4.z = __expf(fmaf(10.f, e2 * inv, -10.f));
  o4.w = __expf(fmaf(10.f, e3 * inv, -10.f));
  *(float4*)(Km + (size_t)r * HW_DIM + tid * 4) = o4;
  const int4 p4 = *(const int4*)(pos + b * HW_DIM + tid * 4);
  const float ov[4] = {o4.x, o4.y, o4.z, o4.w};
  const int pp[4] = {p4.x, p4.y, p4.z, p4.w};
  #pragma unroll
  for (int q = 0; q < 4; q++) if (pp[q] >= 0) Kc[(size_t)r * HW_DIM + pp[q]] = ov[q];
}

// ---------- Sinkhorn: one block (16 waves) per batch, compacted Kmat in registers ----------
__global__ __launch_bounds__(1024) void sinkhorn_kernel(
    const float* __restrict__ Kc, const int* __restrict__ nfg_arr,
    const int* __restrict__ pos, const int* __restrict__ maxIter,
    float* __restrict__ u_out, float* __restrict__ v_out)
{
  const int b = blockIdx.x;
  const int tid = threadIdx.x;
  const int tg = tid >> 6, kg = tid & 63;
  const int nfg = nfg_arr[b];
  const float inv_nfg = 1.0f / (float)nfg;
  const int niter = *maxIter;
  const int njall = (nfg + 63) >> 6;
  __shared__ float part[16][PARTC];
  __shared__ float v_s[HW_DIM];
  __shared__ float u_s[T_DIM];
  const float* KB = Kc + (size_t)(b * T_DIM) * HW_DIM;

  if (njall * 64 <= PARTC) {
    // -------- fast path: rows tg*8+i, compacted cols kg+64*j in registers --------
    const int njr = (njall < NJR) ? njall : NJR;
    float kreg[8][NJR];
    #pragma unroll
    for (int j = 0; j < NJR; j++) {
      #pragma unroll
      for (int i = 0; i < 8; i++) {
        const int col = kg + 64 * j;
        float vle = 0.f;
        if (j < njr && col < nfg) vle = KB[(size_t)(tg * 8 + i) * HW_DIM + col];
        kreg[i][j] = vle;
      }
    }
    float u_reg[8];
    #pragma unroll
    for (int i = 0; i < 8; i++) u_reg[i] = 1.0f / 128.0f;
    const float bv = (tid < nfg) ? inv_nfg : 0.f;

    for (int it = 0; it < niter; ++it) {
      // pass1: Ktu (per-wave partial column sums -> LDS)
      #pragma unroll
      for (int j = 0; j < NJR; j++) {
        if (j < njr) {
          float s = 0.f;
          #pragma unroll
          for (int i = 0; i < 8; i++) s = fmaf(kreg[i][j], u_reg[i], s);
          part[tg][kg + 64 * j] = s;
        }
      }
      for (int j = NJR; j < njall; ++j) {  // rare: nfg in (512,640]
        const int col = kg + 64 * j;
        float s = 0.f;
        #pragma unroll
        for (int i = 0; i < 8; i++) {
          const float kk = (col < nfg) ? KB[(size_t)(tg * 8 + i) * HW_DIM + col] : 0.f;
          s = fmaf(kk, u_reg[i], s);
        }
        part[tg][col] = s;
      }
      __syncthreads();
      {
        float vv = 0.f;
        if (tid < nfg) {
          float s = 0.f;
          #pragma unroll
          for (int g = 0; g < 16; g++) s += part[g][tid];
          vv = bv * fast_rcp(s);
        }
        v_s[tid] = vv;
      }
      __syncthreads();
      // pass2: Kv per row, butterfly across the wave
      float vload[NJR];
      #pragma unroll
      for (int j = 0; j < NJR; j++) vload[j] = (j < njr) ? v_s[kg + 64 * j] : 0.f;
      float kv[8];
      #pragma unroll
      for (int i = 0; i < 8; i++) {
        float s = 0.f;
        #pragma unroll
        for (int j = 0; j < NJR; j++) s = fmaf(kreg[i][j], vload[j], s);
        kv[i] = s;
      }
      for (int j = NJR; j < njall; ++j) {
        const int col = kg + 64 * j;
        const float vv = v_s[col];
        #pragma unroll
        for (int i = 0; i < 8; i++) {
          const float kk = (col < nfg) ? KB[(size_t)(tg * 8 + i) * HW_DIM + col] : 0.f;
          kv[i] = fmaf(kk, vv, kv[i]);
        }
      }
      #pragma unroll
      for (int i = 0; i < 8; i++) {
        #pragma unroll
        for (int o = 32; o; o >>= 1) kv[i] += __shfl_xor(kv[i], o);
        u_reg[i] = 0.0078125f * fast_rcp(kv[i]);
      }
      __syncthreads();
    }
    #pragma unroll
    for (int i = 0; i < 8; i++) if (kg == i) u_out[b * T_DIM + tg * 8 + i] = u_reg[i];
    {
      const int p = pos[b * HW_DIM + tid];
      v_out[b * HW_DIM + tid] = (p >= 0) ? v_s[p] : 0.f;
    }
  } else {
    // -------- slow path (nfg > PARTC; never expected with this data) --------
    if (tid < T_DIM) u_s[tid] = 1.0f / 128.0f;
    const float bv = (tid < nfg) ? inv_nfg : 0.f;
    __syncthreads();
    for (int it = 0; it < niter; ++it) {
      float vv = 0.f;
      if (tid < nfg) {
        float s = 0.f;
        for (int t = 0; t < T_DIM; t++) s = fmaf(KB[(size_t)t * HW_DIM + tid], u_s[t], s);
        vv = bv * fast_rcp(s);
      }
      v_s[tid] = vv;
      __syncthreads();
      #pragma unroll
      for (int r8 = 0; r8 < 8; r8++) {
        const int r = tg * 8 + r8;
        float s = 0.f;
        for (int j = 0; j < 16; j++) {
          const int col = kg + 64 * j;
          if (col < nfg) s = fmaf(KB[(size_t)r * HW_DIM + col], v_s[col], s);
        }
        #pragma unroll
        for (int o = 32; o; o >>= 1) s += __shfl_xor(s, o);
        if (kg == 0) u_s[r] = 0.0078125f * fast_rcp(s);
      }
      __syncthreads();
    }
    if (tid < T_DIM) u_out[b * T_DIM + tid] = u_s[tid];
    const int p = pos[b * HW_DIM + tid];
    v_out[b * HW_DIM + tid] = (p >= 0) ? v_s[p] : 0.f;
  }
}

// ---------- S_hat = u * Km * v ----------
__global__ __launch_bounds__(256) void shat_kernel(const float* __restrict__ Km,
    const float* __restrict__ u, const float* __restrict__ v, float* __restrict__ Sh)
{
  const int r = blockIdx.x;
  const int b = r >> 7;
  const int tid = threadIdx.x;
  const float uu = u[r];
  const float4 km = *(const float4*)(Km + (size_t)r * HW_DIM + tid * 4);
  const float4 vv = *(const float4*)(v + (size_t)b * HW_DIM + tid * 4);
  float4 o;
  o.x = uu * km.x * vv.x; o.y = uu * km.y * vv.y;
  o.z = uu * km.z * vv.z; o.w = uu * km.w * vv.w;
  *(float4*)(Sh + (size_t)r * HW_DIM + tid * 4) = o;
}

extern "C" void kernel_launch(void* const* d_in, const int* in_sizes, int n_in,
                              void* d_out, int out_size, void* d_ws, size_t ws_size,
                              hipStream_t stream)
{
  const float* F_a  = (const float*)d_in[0];
  const float* F_s  = (const float*)d_in[1];
  const int*   M_s  = (const int*)  d_in[2];
  const float* W_aQ = (const float*)d_in[3];
  const float* b_aQ = (const float*)d_in[4];
  const float* W_sK = (const float*)d_in[5];
  const float* b_sK = (const float*)d_in[6];
  const float* W_sV = (const float*)d_in[7];
  const float* b_sV = (const float*)d_in[8];
  const float* W1   = (const float*)d_in[9];
  const float* b1   = (const float*)d_in[10];
  const float* W2   = (const float*)d_in[11];
  const float* b2   = (const float*)d_in[12];
  const int* maxIter = (const int*)d_in[13];
  float* out = (float*)d_out;

  float* f = (float*)d_ws;
  float* Mm = f;  f += 256 * 256;
  float* w0 = f;  f += 256;
  float* wq = f;  f += 256;
  float* s0 = f;  f += 4;
  float* P  = f;  f += 2048 * 256;      // reused as A2 after QK gemm
  float* qb = f;  f += 2048;
  float* QK = f;  f += 2048 * 1024;     // reused as S_hat after softmax
  float* Km = f;  f += 2048 * 1024;
  float* Kc = f;  f += 2048 * 1024;
  float* u  = f;  f += 2048;
  float* v  = f;  f += 16 * 1024;
  float* o1 = f;  f += 2048 * 256;
  float* hh = f;  f += 2048 * 768;
  int* nfg  = (int*)f;  f += 16;
  int* pos  = (int*)f;  f += 16 * 1024;
  float* A2 = P;
  float* Sh = QK;

  // mask prep + bias folds
  prep_kernel<<<16, 256, 0, stream>>>(M_s, nfg, pos);
  wvec_kernel<<<129, 256, 0, stream>>>(W_aQ, b_aQ, W_sK, b_sK, w0, wq, s0);
  // Mm = W_aQ @ W_sK^T   [256,256] K=1024
  gemm_kernel<true,false,0><<<dim3(4,4,1),256,0,stream>>>(W_aQ,1024,0, W_sK,1024,0, Mm,256,0, 256,256,1024, nullptr,0,0.f);
  // P = F_a @ Mm + w0    [2048,256] K=256
  gemm_kernel<false,false,1><<<dim3(4,32,1),256,0,stream>>>(F_a,256,0, Mm,256,0, P,256,0, 2048,256,256, w0,0,1.0f);
  qb_kernel<<<512, 256, 0, stream>>>(F_a, wq, s0, qb);
  // QK[b] = P[b] @ F_s[b]^T + qb   [128,1024] K=256, batched
  gemm_kernel<true,false,2><<<dim3(16,2,16),256,0,stream>>>(P,256,128*256, F_s,256,1024*256, QK,1024,128*1024, 128,1024,256, qb,128,0.f);
  softmax_kernel<<<2048, 256, 0, stream>>>(QK, M_s, pos, Km, Kc);
  sinkhorn_kernel<<<16, 1024, 0, stream>>>(Kc, nfg, pos, maxIter, u, v);
  shat_kernel<<<2048, 256, 0, stream>>>(Km, u, v, Sh);
  // A2[b] = S_hat[b] @ F_s[b]   [128,256] K=1024, batched
  gemm_kernel<false,false,0><<<dim3(4,2,16),256,0,stream>>>(Sh,1024,128*1024, F_s,256,1024*256, A2,256,128*256, 128,256,1024, nullptr,0,0.f);
  // o1 = A2 @ W_sV + (1/T)*b_sV  [2048,256] K=256
  gemm_kernel<false,false,1><<<dim3(4,32,1),256,0,stream>>>(A2,256,0, W_sV,256,0, o1,256,0, 2048,256,256, b_sV,0, 0.0078125f);
  // hh = relu(o1 @ W1 + b1)      [2048,768] K=256
  gemm_kernel<false,true,1><<<dim3(12,32,1),256,0,stream>>>(o1,256,0, W1,768,0, hh,768,0, 2048,768,256, b1,0, 1.0f);
  // out = hh @ W2 + b2           [2048,256] K=768
  gemm_kernel<false,false,1><<<dim3(4,32,1),256,0,stream>>>(hh,768,0, W2,256,0, out,256,0, 2048,256,768, b2,0, 1.0f);
}

// Round 5
// 356.211 us; speedup vs baseline: 1.8831x; 1.8831x over previous
//
#include <hip/hip_runtime.h>
#include <cstdint>

#define T_DIM 128
#define C_DIM 256
#define HW_DIM 1024
#define B_DIM 16
#define NJR 8       // register j-blocks (64 cols each) in sinkhorn fast path
#define PARTC 640   // max compacted cols handled by fast path
#define CHK 10      // convergence check period
#define TOL 2e-6f   // relative u-change tolerance

__device__ __forceinline__ float fast_rcp(float x) {
#if defined(__has_builtin)
#if __has_builtin(__builtin_amdgcn_rcpf)
  return __builtin_amdgcn_rcpf(x);
#else
  return 1.0f / x;
#endif
#else
  return 1.0f / x;
#endif
}

// ---------- prep: per-batch fg count + compact position map ----------
__global__ __launch_bounds__(256) void prep_kernel(const int* __restrict__ Ms,
                                                   int* __restrict__ nfg,
                                                   int* __restrict__ pos)
{
  const int b = blockIdx.x, tid = threadIdx.x;
  const int4 m4 = *(const int4*)(Ms + b * HW_DIM + tid * 4);
  const int c = m4.x + m4.y + m4.z + m4.w;
  const int lane = tid & 63, w = tid >> 6;
  int pre = c;
  #pragma unroll
  for (int o = 1; o < 64; o <<= 1) { int t = __shfl_up(pre, (unsigned)o); if (lane >= o) pre += t; }
  __shared__ int wtot[4];
  if (lane == 63) wtot[w] = pre;
  __syncthreads();
  int base = 0;
  #pragma unroll
  for (int i = 0; i < 4; i++) if (i < w) base += wtot[i];
  const int excl = base + pre - c;
  if (tid == 0) nfg[b] = wtot[0] + wtot[1] + wtot[2] + wtot[3];
  int p = excl;
  const int mm[4] = {m4.x, m4.y, m4.z, m4.w};
  #pragma unroll
  for (int q = 0; q < 4; q++) {
    pos[b * HW_DIM + tid * 4 + q] = mm[q] ? p : -1;
    p += mm[q];
  }
}

// ---------- bias-fold vectors: w0 = b_aQ@W_sK^T, wq = W_aQ@b_sK, s0 = b_aQ.b_sK ----------
__global__ __launch_bounds__(256) void wvec_kernel(
    const float* __restrict__ W_aQ, const float* __restrict__ b_aQ,
    const float* __restrict__ W_sK, const float* __restrict__ b_sK,
    float* __restrict__ w0, float* __restrict__ wq, float* __restrict__ s0)
{
  const int wid = blockIdx.x * 4 + (threadIdx.x >> 6);
  const int lane = threadIdx.x & 63;
  if (wid > 512) return;
  float acc = 0.f;
  if (wid < 256) {
    #pragma unroll 4
    for (int j = 0; j < 16; j++) { int h = lane + 64 * j; acc = fmaf(b_aQ[h], W_sK[(size_t)wid * 1024 + h], acc); }
  } else if (wid < 512) {
    const int c = wid - 256;
    #pragma unroll 4
    for (int j = 0; j < 16; j++) { int h = lane + 64 * j; acc = fmaf(W_aQ[(size_t)c * 1024 + h], b_sK[h], acc); }
  } else {
    #pragma unroll 4
    for (int j = 0; j < 16; j++) { int h = lane + 64 * j; acc = fmaf(b_aQ[h], b_sK[h], acc); }
  }
  #pragma unroll
  for (int o = 32; o; o >>= 1) acc += __shfl_xor(acc, o);
  if (lane == 0) {
    if (wid < 256) w0[wid] = acc;
    else if (wid < 512) wq[wid - 256] = acc;
    else s0[0] = acc;
  }
}

// ---------- qb[r] = F_a[r,:].wq + s0 ----------
__global__ __launch_bounds__(256) void qb_kernel(const float* __restrict__ F_a,
    const float* __restrict__ wq, const float* __restrict__ s0, float* __restrict__ qb)
{
  const int r = blockIdx.x * 4 + (threadIdx.x >> 6);
  const int lane = threadIdx.x & 63;
  float acc = 0.f;
  #pragma unroll
  for (int j = 0; j < 4; j++) { int c = lane + 64 * j; acc = fmaf(F_a[(size_t)r * 256 + c], wq[c], acc); }
  #pragma unroll
  for (int o = 32; o; o >>= 1) acc += __shfl_xor(acc, o);
  if (lane == 0) qb[r] = acc + s0[0];
}

// ---------- generic 64x64 tiled fp32 GEMM: C = A * (BT ? B^T : B) + bias ----------
template<bool BT, bool RELU, int BIAS>
__global__ __launch_bounds__(256) void gemm_kernel(
    const float* __restrict__ A, int lda, long long sA,
    const float* __restrict__ B, int ldb, long long sB,
    float* __restrict__ C, int ldc, long long sC,
    int M, int N, int K,
    const float* __restrict__ bias, int sBias, float bscale)
{
  __shared__ float As[16][68];
  __shared__ float Bs[16][68];
  const int bz = blockIdx.z;
  A += (size_t)sA * bz;  B += (size_t)sB * bz;  C += (size_t)sC * bz;
  const int m0 = blockIdx.y * 64, n0 = blockIdx.x * 64;
  const int tid = threadIdx.x;
  const int tx = tid & 15, ty = tid >> 4;
  const int lrow = tid >> 2, lk = (tid & 3) * 4;
  const int brow = tid >> 4, bcol = (tid & 15) * 4;
  float acc[4][4];
  #pragma unroll
  for (int i = 0; i < 4; i++)
    #pragma unroll
    for (int j = 0; j < 4; j++) acc[i][j] = 0.f;

  for (int k0 = 0; k0 < K; k0 += 16) {
    const float4 av = *(const float4*)(A + (size_t)(m0 + lrow) * lda + (k0 + lk));
    As[lk + 0][lrow] = av.x; As[lk + 1][lrow] = av.y;
    As[lk + 2][lrow] = av.z; As[lk + 3][lrow] = av.w;
    if (BT) {
      const float4 bv = *(const float4*)(B + (size_t)(n0 + lrow) * ldb + (k0 + lk));
      Bs[lk + 0][lrow] = bv.x; Bs[lk + 1][lrow] = bv.y;
      Bs[lk + 2][lrow] = bv.z; Bs[lk + 3][lrow] = bv.w;
    } else {
      const float4 bv = *(const float4*)(B + (size_t)(k0 + brow) * ldb + (n0 + bcol));
      *(float4*)&Bs[brow][bcol] = bv;
    }
    __syncthreads();
    #pragma unroll
    for (int kk = 0; kk < 16; ++kk) {
      const float4 a4 = *(const float4*)&As[kk][ty * 4];
      const float4 b4 = *(const float4*)&Bs[kk][tx * 4];
      const float ar[4] = {a4.x, a4.y, a4.z, a4.w};
      const float br[4] = {b4.x, b4.y, b4.z, b4.w};
      #pragma unroll
      for (int i = 0; i < 4; i++)
        #pragma unroll
        for (int j = 0; j < 4; j++)
          acc[i][j] = fmaf(ar[i], br[j], acc[i][j]);
    }
    __syncthreads();
  }
  #pragma unroll
  for (int i = 0; i < 4; i++) {
    const int m = m0 + ty * 4 + i;
    float rowb = 0.f;
    if (BIAS == 2) rowb = bias[(size_t)sBias * bz + m];
    float vtmp[4];
    #pragma unroll
    for (int j = 0; j < 4; j++) {
      float val = acc[i][j];
      if (BIAS == 1) val += bscale * bias[n0 + tx * 4 + j];
      if (BIAS == 2) val += rowb;
      if (RELU) val = fmaxf(val, 0.f);
      vtmp[j] = val;
    }
    float4 o4; o4.x = vtmp[0]; o4.y = vtmp[1]; o4.z = vtmp[2]; o4.w = vtmp[3];
    *(float4*)(C + (size_t)m * ldc + (n0 + tx * 4)) = o4;
  }
}

// ---------- row softmax (masked) + Kmat = exp(10*(S-1)); writes full + compacted ----------
__global__ __launch_bounds__(256) void softmax_kernel(
    const float* __restrict__ QK, const int* __restrict__ Ms,
    const int* __restrict__ pos, float* __restrict__ Km, float* __restrict__ Kc)
{
  const int r = blockIdx.x;          // 0..2047 (b*128+t)
  const int b = r >> 7;
  const int tid = threadIdx.x;
  const float4 x = *(const float4*)(QK + (size_t)r * HW_DIM + tid * 4);
  const int4 m4 = *(const int4*)(Ms + b * HW_DIM + tid * 4);
  float mx = -3.0e38f;
  if (m4.x) mx = x.x;
  if (m4.y) mx = fmaxf(mx, x.y);
  if (m4.z) mx = fmaxf(mx, x.z);
  if (m4.w) mx = fmaxf(mx, x.w);
  #pragma unroll
  for (int o = 32; o; o >>= 1) mx = fmaxf(mx, __shfl_xor(mx, o));
  __shared__ float red[4];
  const int lane = tid & 63, w = tid >> 6;
  if (lane == 0) red[w] = mx;
  __syncthreads();
  const float gmax = fmaxf(fmaxf(red[0], red[1]), fmaxf(red[2], red[3]));
  __syncthreads();
  const float e0 = m4.x ? __expf(x.x - gmax) : 0.f;
  const float e1 = m4.y ? __expf(x.y - gmax) : 0.f;
  const float e2 = m4.z ? __expf(x.z - gmax) : 0.f;
  const float e3 = m4.w ? __expf(x.w - gmax) : 0.f;
  float s = e0 + e1 + e2 + e3;
  #pragma unroll
  for (int o = 32; o; o >>= 1) s += __shfl_xor(s, o);
  if (lane == 0) red[w] = s;
  __syncthreads();
  const float inv = 1.0f / (red[0] + red[1] + red[2] + red[3]);
  float4 o4;
  o4.x = __expf(fmaf(10.f, e0 * inv, -10.f));
  o4.y = __expf(fmaf(10.f, e1 * inv, -10.f));
  o4.z = __expf(fmaf(10.f, e2 * inv, -10.f));
  o4.w = __expf(fmaf(10.f, e3 * inv, -10.f));
  *(float4*)(Km + (size_t)r * HW_DIM + tid * 4) = o4;
  const int4 p4 = *(const int4*)(pos + b * HW_DIM + tid * 4);
  const float ov[4] = {o4.x, o4.y, o4.z, o4.w};
  const int pp[4] = {p4.x, p4.y, p4.z, p4.w};
  #pragma unroll
  for (int q = 0; q < 4; q++) if (pp[q] >= 0) Kc[(size_t)r * HW_DIM + pp[q]] = ov[q];
}

// ---------- Sinkhorn: one block (16 waves) per batch, compacted Kmat in registers ----------
// Round-3 fold/barrier/early-exit structure + RESTORED tail loops (cols 512..nfg-1,
// hit by ~50% of batches; dropping them was the round-3 correctness bug).
__global__ __launch_bounds__(1024, 4) void sinkhorn_kernel(
    const float* __restrict__ Kc, const int* __restrict__ nfg_arr,
    const int* __restrict__ pos, const int* __restrict__ maxIter,
    float* __restrict__ u_out, float* __restrict__ v_out)
{
  const int b = blockIdx.x;
  const int tid = threadIdx.x;
  const int tg = tid >> 6, kg = tid & 63;
  const int nfg = nfg_arr[b];
  const float inv_nfg = 1.0f / (float)nfg;
  const int niter = *maxIter;
  const int njall = (nfg + 63) >> 6;
  __shared__ float part[16][PARTC];
  __shared__ float v_s[HW_DIM];
  __shared__ float u_s[T_DIM];
  __shared__ int conv;
  const float* KB = Kc + (size_t)(b * T_DIM) * HW_DIM;

  if (njall * 64 <= PARTC) {
    // -------- fast path: rows tg*8+i, compacted cols kg+64*j in registers --------
    const int njr = (njall < NJR) ? njall : NJR;
    float kreg[8][NJR];
    #pragma unroll
    for (int j = 0; j < NJR; j++) {
      #pragma unroll
      for (int i = 0; i < 8; i++) {
        const int col = kg + 64 * j;
        float vle = 0.f;
        if (j < njr && col < nfg) vle = KB[(size_t)(tg * 8 + i) * HW_DIM + col];
        kreg[i][j] = vle;
      }
    }
    if (tid < T_DIM) u_s[tid] = 1.0f / 128.0f;
    if (tid == 0) conv = 1;
    const float bv = (tid < nfg) ? inv_nfg : 0.f;
    float u_prev = 1.0f / 128.0f;   // this lane's row (tg*8 + (kg&7)) value
    __syncthreads();

    for (int it = 0; it < niter; ++it) {
      // ---- pass1: Ktu. u via wave-internal LDS broadcast reads. ----
      float uu[8];
      #pragma unroll
      for (int i = 0; i < 8; i++) uu[i] = u_s[tg * 8 + i];
      #pragma unroll
      for (int j = 0; j < NJR; j++) {
        if (j < njr) {
          float s = 0.f;
          #pragma unroll
          for (int i = 0; i < 8; i++) s = fmaf(kreg[i][j], uu[i], s);
          part[tg][kg + 64 * j] = s;
        }
      }
      for (int j = NJR; j < njall; ++j) {   // tail cols 512..nfg-1 (~50% of batches)
        const int col = kg + 64 * j;
        float s = 0.f;
        #pragma unroll
        for (int i = 0; i < 8; i++) {
          const float kk = (col < nfg) ? KB[(size_t)(tg * 8 + i) * HW_DIM + col] : 0.f;
          s = fmaf(kk, uu[i], s);
        }
        part[tg][col] = s;
      }
      __syncthreads();                                        // B1
      // early-exit read: result of the check performed at iter it-1
      if (it != 0 && (it % CHK) == 0) {
        if (conv) break;                                      // block-uniform
      }
      const int checknow = ((it % CHK) == (CHK - 1));
      if (checknow && tid == 0) conv = 1;                     // re-arm between B1/B2
      // ---- v-step ----
      {
        float vv = 0.f;
        if (tid < nfg) {
          float s = 0.f;
          #pragma unroll
          for (int g = 0; g < 16; g++) s += part[g][tid];
          vv = bv * fast_rcp(s);
        }
        v_s[tid] = vv;
      }
      __syncthreads();                                        // B2
      // ---- pass2: Kv partials, then fold 8 rows x 64 lanes with 10 shfl ----
      float vload[NJR];
      #pragma unroll
      for (int j = 0; j < NJR; j++) vload[j] = (j < njr) ? v_s[kg + 64 * j] : 0.f;
      float kv[8];
      #pragma unroll
      for (int i = 0; i < 8; i++) {
        float s = 0.f;
        #pragma unroll
        for (int j = 0; j < NJR; j++) s = fmaf(kreg[i][j], vload[j], s);
        kv[i] = s;
      }
      for (int j = NJR; j < njall; ++j) {   // tail cols 512..nfg-1
        const int col = kg + 64 * j;
        const float vv = v_s[col];
        #pragma unroll
        for (int i = 0; i < 8; i++) {
          const float kk = (col < nfg) ? KB[(size_t)(tg * 8 + i) * HW_DIM + col] : 0.f;
          kv[i] = fmaf(kk, vv, kv[i]);
        }
      }
      // fold value-bit k into lane-bit k (k=0,1,2): 4+2+1 shfl
      float k2[4];
      #pragma unroll
      for (int p = 0; p < 4; p++) {
        const float g = (kg & 1) ? kv[2 * p] : kv[2 * p + 1];
        const float r = __shfl_xor(g, 1);
        k2[p] = ((kg & 1) ? kv[2 * p + 1] : kv[2 * p]) + r;
      }
      float k3[2];
      #pragma unroll
      for (int q = 0; q < 2; q++) {
        const float g = (kg & 2) ? k2[2 * q] : k2[2 * q + 1];
        const float r = __shfl_xor(g, 2);
        k3[q] = ((kg & 2) ? k2[2 * q + 1] : k2[2 * q]) + r;
      }
      float t;
      {
        const float g = (kg & 4) ? k3[0] : k3[1];
        const float r = __shfl_xor(g, 4);
        t = ((kg & 4) ? k3[1] : k3[0]) + r;
      }
      // butterfly across 8-lane groups: all lanes end with total of row tg*8+(kg&7)
      t += __shfl_xor(t, 8);
      t += __shfl_xor(t, 16);
      t += __shfl_xor(t, 32);
      const float u_new = 0.0078125f * fast_rcp(t);
      if (kg < 8) u_s[tg * 8 + kg] = u_new;                   // wave-internal write
      if (checknow) {
        const int ok = (fabsf(u_new - u_prev) <= TOL * fabsf(u_new));
        if (!__all(ok) && kg == 0) conv = 0;                  // post-B2 store
      }
      u_prev = u_new;
      // no loop-end barrier: part reuse guarded by B2, v_s reuse by next B1
    }
    __syncthreads();
    if (tid < T_DIM) u_out[b * T_DIM + tid] = u_s[tid];
    {
      const int p = pos[b * HW_DIM + tid];
      v_out[b * HW_DIM + tid] = (p >= 0) ? v_s[p] : 0.f;
    }
  } else {
    // -------- slow path (nfg > PARTC; never expected with this data) --------
    if (tid < T_DIM) u_s[tid] = 1.0f / 128.0f;
    const float bv = (tid < nfg) ? inv_nfg : 0.f;
    __syncthreads();
    for (int it = 0; it < niter; ++it) {
      float vv = 0.f;
      if (tid < nfg) {
        float s = 0.f;
        for (int t = 0; t < T_DIM; t++) s = fmaf(KB[(size_t)t * HW_DIM + tid], u_s[t], s);
        vv = bv * fast_rcp(s);
      }
      v_s[tid] = vv;
      __syncthreads();
      #pragma unroll
      for (int r8 = 0; r8 < 8; r8++) {
        const int r = tg * 8 + r8;
        float s = 0.f;
        for (int j = 0; j < 16; j++) {
          const int col = kg + 64 * j;
          if (col < nfg) s = fmaf(KB[(size_t)r * HW_DIM + col], v_s[col], s);
        }
        #pragma unroll
        for (int o = 32; o; o >>= 1) s += __shfl_xor(s, o);
        if (kg == 0) u_s[r] = 0.0078125f * fast_rcp(s);
      }
      __syncthreads();
    }
    if (tid < T_DIM) u_out[b * T_DIM + tid] = u_s[tid];
    const int p = pos[b * HW_DIM + tid];
    v_out[b * HW_DIM + tid] = (p >= 0) ? v_s[p] : 0.f;
  }
}

// ---------- S_hat = u * Km * v ----------
__global__ __launch_bounds__(256) void shat_kernel(const float* __restrict__ Km,
    const float* __restrict__ u, const float* __restrict__ v, float* __restrict__ Sh)
{
  const int r = blockIdx.x;
  const int b = r >> 7;
  const int tid = threadIdx.x;
  const float uu = u[r];
  const float4 km = *(const float4*)(Km + (size_t)r * HW_DIM + tid * 4);
  const float4 vv = *(const float4*)(v + (size_t)b * HW_DIM + tid * 4);
  float4 o;
  o.x = uu * km.x * vv.x; o.y = uu * km.y * vv.y;
  o.z = uu * km.z * vv.z; o.w = uu * km.w * vv.w;
  *(float4*)(Sh + (size_t)r * HW_DIM + tid * 4) = o;
}

extern "C" void kernel_launch(void* const* d_in, const int* in_sizes, int n_in,
                              void* d_out, int out_size, void* d_ws, size_t ws_size,
                              hipStream_t stream)
{
  const float* F_a  = (const float*)d_in[0];
  const float* F_s  = (const float*)d_in[1];
  const int*   M_s  = (const int*)  d_in[2];
  const float* W_aQ = (const float*)d_in[3];
  const float* b_aQ = (const float*)d_in[4];
  const float* W_sK = (const float*)d_in[5];
  const float* b_sK = (const float*)d_in[6];
  const float* W_sV = (const float*)d_in[7];
  const float* b_sV = (const float*)d_in[8];
  const float* W1   = (const float*)d_in[9];
  const float* b1   = (const float*)d_in[10];
  const float* W2   = (const float*)d_in[11];
  const float* b2   = (const float*)d_in[12];
  const int* maxIter = (const int*)d_in[13];
  float* out = (float*)d_out;

  float* f = (float*)d_ws;
  float* Mm = f;  f += 256 * 256;
  float* w0 = f;  f += 256;
  float* wq = f;  f += 256;
  float* s0 = f;  f += 4;
  float* P  = f;  f += 2048 * 256;      // reused as A2 after QK gemm
  float* qb = f;  f += 2048;
  float* QK = f;  f += 2048 * 1024;     // reused as S_hat after softmax
  float* Km = f;  f += 2048 * 1024;
  float* Kc = f;  f += 2048 * 1024;
  float* u  = f;  f += 2048;
  float* v  = f;  f += 16 * 1024;
  float* o1 = f;  f += 2048 * 256;
  float* hh = f;  f += 2048 * 768;
  int* nfg  = (int*)f;  f += 16;
  int* pos  = (int*)f;  f += 16 * 1024;
  float* A2 = P;
  float* Sh = QK;

  // mask prep + bias folds
  prep_kernel<<<16, 256, 0, stream>>>(M_s, nfg, pos);
  wvec_kernel<<<129, 256, 0, stream>>>(W_aQ, b_aQ, W_sK, b_sK, w0, wq, s0);
  // Mm = W_aQ @ W_sK^T   [256,256] K=1024
  gemm_kernel<true,false,0><<<dim3(4,4,1),256,0,stream>>>(W_aQ,1024,0, W_sK,1024,0, Mm,256,0, 256,256,1024, nullptr,0,0.f);
  // P = F_a @ Mm + w0    [2048,256] K=256
  gemm_kernel<false,false,1><<<dim3(4,32,1),256,0,stream>>>(F_a,256,0, Mm,256,0, P,256,0, 2048,256,256, w0,0,1.0f);
  qb_kernel<<<512, 256, 0, stream>>>(F_a, wq, s0, qb);
  // QK[b] = P[b] @ F_s[b]^T + qb   [128,1024] K=256, batched
  gemm_kernel<true,false,2><<<dim3(16,2,16),256,0,stream>>>(P,256,128*256, F_s,256,1024*256, QK,1024,128*1024, 128,1024,256, qb,128,0.f);
  softmax_kernel<<<2048, 256, 0, stream>>>(QK, M_s, pos, Km, Kc);
  sinkhorn_kernel<<<16, 1024, 0, stream>>>(Kc, nfg, pos, maxIter, u, v);
  shat_kernel<<<2048, 256, 0, stream>>>(Km, u, v, Sh);
  // A2[b] = S_hat[b] @ F_s[b]   [128,256] K=1024, batched
  gemm_kernel<false,false,0><<<dim3(4,2,16),256,0,stream>>>(Sh,1024,128*1024, F_s,256,1024*256, A2,256,128*256, 128,256,1024, nullptr,0,0.f);
  // o1 = A2 @ W_sV + (1/T)*b_sV  [2048,256] K=256
  gemm_kernel<false,false,1><<<dim3(4,32,1),256,0,stream>>>(A2,256,0, W_sV,256,0, o1,256,0, 2048,256,256, b_sV,0, 0.0078125f);
  // hh = relu(o1 @ W1 + b1)      [2048,768] K=256
  gemm_kernel<false,true,1><<<dim3(12,32,1),256,0,stream>>>(o1,256,0, W1,768,0, hh,768,0, 2048,768,256, b1,0, 1.0f);
  // out = hh @ W2 + b2           [2048,256] K=768
  gemm_kernel<false,false,1><<<dim3(4,32,1),256,0,stream>>>(hh,768,0, W2,256,0, out,256,0, 2048,256,768, b2,0, 1.0f);
}

// Round 6
// 210.595 us; speedup vs baseline: 3.1852x; 1.6915x over previous
//
#include <hip/hip_runtime.h>
#include <cstdint>

#define T_DIM 128
#define C_DIM 256
#define HW_DIM 1024
#define B_DIM 16
#define NJR 8       // register j-blocks (64 cols each) in sinkhorn fast path
#define PARTC 640   // max compacted cols handled by fast path
#define CHK 10      // convergence check period
#define TOL 2e-6f   // relative u-change tolerance
#define LDP 72      // padded LDS row pitch (bf16 elems) for 64-wide tiles

typedef __bf16 bf16x8 __attribute__((ext_vector_type(8)));
typedef float f32x4 __attribute__((ext_vector_type(4)));

__device__ __forceinline__ float fast_rcp(float x) {
  return __builtin_amdgcn_rcpf(x);
}

__device__ __forceinline__ unsigned short f2bf(float x) {  // RTNE fp32->bf16
  unsigned u = __float_as_uint(x);
  u += 0x7fffu + ((u >> 16) & 1u);
  return (unsigned short)(u >> 16);
}

// ---------- prep: per-batch fg count + compact position map ----------
__global__ __launch_bounds__(256) void prep_kernel(const int* __restrict__ Ms,
                                                   int* __restrict__ nfg,
                                                   int* __restrict__ pos)
{
  const int b = blockIdx.x, tid = threadIdx.x;
  const int4 m4 = *(const int4*)(Ms + b * HW_DIM + tid * 4);
  const int c = m4.x + m4.y + m4.z + m4.w;
  const int lane = tid & 63, w = tid >> 6;
  int pre = c;
  #pragma unroll
  for (int o = 1; o < 64; o <<= 1) { int t = __shfl_up(pre, (unsigned)o); if (lane >= o) pre += t; }
  __shared__ int wtot[4];
  if (lane == 63) wtot[w] = pre;
  __syncthreads();
  int base = 0;
  #pragma unroll
  for (int i = 0; i < 4; i++) if (i < w) base += wtot[i];
  const int excl = base + pre - c;
  if (tid == 0) nfg[b] = wtot[0] + wtot[1] + wtot[2] + wtot[3];
  int p = excl;
  const int mm[4] = {m4.x, m4.y, m4.z, m4.w};
  #pragma unroll
  for (int q = 0; q < 4; q++) {
    pos[b * HW_DIM + tid * 4 + q] = mm[q] ? p : -1;
    p += mm[q];
  }
}

// ---------- bias-fold vectors: w0 = b_aQ@W_sK^T, wq = W_aQ@b_sK, s0 = b_aQ.b_sK ----------
__global__ __launch_bounds__(256) void wvec_kernel(
    const float* __restrict__ W_aQ, const float* __restrict__ b_aQ,
    const float* __restrict__ W_sK, const float* __restrict__ b_sK,
    float* __restrict__ w0, float* __restrict__ wq, float* __restrict__ s0)
{
  const int wid = blockIdx.x * 4 + (threadIdx.x >> 6);
  const int lane = threadIdx.x & 63;
  if (wid > 512) return;
  float acc = 0.f;
  if (wid < 256) {
    #pragma unroll 4
    for (int j = 0; j < 16; j++) { int h = lane + 64 * j; acc = fmaf(b_aQ[h], W_sK[(size_t)wid * 1024 + h], acc); }
  } else if (wid < 512) {
    const int c = wid - 256;
    #pragma unroll 4
    for (int j = 0; j < 16; j++) { int h = lane + 64 * j; acc = fmaf(W_aQ[(size_t)c * 1024 + h], b_sK[h], acc); }
  } else {
    #pragma unroll 4
    for (int j = 0; j < 16; j++) { int h = lane + 64 * j; acc = fmaf(b_aQ[h], b_sK[h], acc); }
  }
  #pragma unroll
  for (int o = 32; o; o >>= 1) acc += __shfl_xor(acc, o);
  if (lane == 0) {
    if (wid < 256) w0[wid] = acc;
    else if (wid < 512) wq[wid - 256] = acc;
    else s0[0] = acc;
  }
}

// ---------- qb[r] = F_a[r,:].wq + s0 ----------
__global__ __launch_bounds__(256) void qb_kernel(const float* __restrict__ F_a,
    const float* __restrict__ wq, const float* __restrict__ s0, float* __restrict__ qb)
{
  const int r = blockIdx.x * 4 + (threadIdx.x >> 6);
  const int lane = threadIdx.x & 63;
  float acc = 0.f;
  #pragma unroll
  for (int j = 0; j < 4; j++) { int c = lane + 64 * j; acc = fmaf(F_a[(size_t)r * 256 + c], wq[c], acc); }
  #pragma unroll
  for (int o = 32; o; o >>= 1) acc += __shfl_xor(acc, o);
  if (lane == 0) qb[r] = acc + s0[0];
}

// ---------- fp32 -> bf16 straight convert (8 elems/thread) ----------
__global__ __launch_bounds__(256) void cvt_kernel(const float* __restrict__ S,
    unsigned short* __restrict__ D, int n8)
{
  const int i = blockIdx.x * 256 + threadIdx.x;
  if (i >= n8) return;
  const float4 x0 = ((const float4*)S)[2 * i];
  const float4 x1 = ((const float4*)S)[2 * i + 1];
  uint4 o;
  o.x = (unsigned)f2bf(x0.x) | ((unsigned)f2bf(x0.y) << 16);
  o.y = (unsigned)f2bf(x0.z) | ((unsigned)f2bf(x0.w) << 16);
  o.z = (unsigned)f2bf(x1.x) | ((unsigned)f2bf(x1.y) << 16);
  o.w = (unsigned)f2bf(x1.z) | ((unsigned)f2bf(x1.w) << 16);
  ((uint4*)D)[i] = o;
}

// ---------- fp32[R,C] -> bf16[C,R] transpose-convert, 32x32 tiles ----------
__global__ __launch_bounds__(256) void cvtT_kernel(const float* __restrict__ S, int R, int C,
    long long sS, unsigned short* __restrict__ D, long long sD)
{
  __shared__ float t[32][33];
  const int bz = blockIdx.z;
  S += sS * bz;  D += sD * bz;
  const int c0 = blockIdx.x * 32, r0 = blockIdx.y * 32;
  const int tx = threadIdx.x & 31, ty = threadIdx.x >> 5;
  #pragma unroll
  for (int i = 0; i < 4; i++) t[ty + 8 * i][tx] = S[(size_t)(r0 + ty + 8 * i) * C + c0 + tx];
  __syncthreads();
  #pragma unroll
  for (int i = 0; i < 4; i++) {
    const int c = ty + 8 * i;
    D[(size_t)(c0 + c) * R + r0 + tx] = f2bf(t[tx][c]);
  }
}

// ---------- bf16 MFMA GEMM: C[M,N] = A[M,K] * B[N,K]^T (+bias, relu) ----------
// A,B row-major bf16 (K contiguous). 64x64 tile, 4 waves, wave = 32x32 via 2x2
// mfma_f32_16x16x32_bf16. BIAS: 0 none, 1 col fp32*bscale, 2 row fp32 per batch.
template<int BIAS, bool RELU, bool OUTBF>
__global__ __launch_bounds__(256) void mgemm_kernel(
    const unsigned short* __restrict__ A, int lda, long long sA,
    const unsigned short* __restrict__ B, int ldb, long long sB,
    void* __restrict__ Cv, int ldc, long long sC,
    int K, const float* __restrict__ bias, int sBias, float bscale)
{
  __shared__ __align__(16) unsigned short As[64 * LDP];
  __shared__ __align__(16) unsigned short Bs[64 * LDP];
  const int bz = blockIdx.z;
  A += sA * bz;  B += sB * bz;
  const int m0 = blockIdx.y * 64, n0 = blockIdx.x * 64;
  const int tid = threadIdx.x;
  const int lr = tid >> 2, lc = (tid & 3) * 16;      // staging: row, col16
  const int w = tid >> 6, lane = tid & 63;
  const int wm = (w >> 1) * 32, wn = (w & 1) * 32;   // wave's 32x32 quadrant
  const int fr = lane & 15, fk = (lane >> 4) * 8;    // fragment row/col + k-base
  const f32x4 zz = {0.f, 0.f, 0.f, 0.f};
  f32x4 acc[2][2] = {{zz, zz}, {zz, zz}};
  const size_t abase = (size_t)(m0 + lr) * lda + lc;
  const size_t bbase = (size_t)(n0 + lr) * ldb + lc;
  uint4 a0 = *(const uint4*)(A + abase);
  uint4 a1 = *(const uint4*)(A + abase + 8);
  uint4 b0 = *(const uint4*)(B + bbase);
  uint4 b1 = *(const uint4*)(B + bbase + 8);
  const int NT = K >> 6;
  for (int t = 0; t < NT; ++t) {
    __syncthreads();
    *(uint4*)&As[lr * LDP + lc] = a0;  *(uint4*)&As[lr * LDP + lc + 8] = a1;
    *(uint4*)&Bs[lr * LDP + lc] = b0;  *(uint4*)&Bs[lr * LDP + lc + 8] = b1;
    __syncthreads();
    if (t + 1 < NT) {   // prefetch next tile while computing this one
      const size_t ka = abase + (size_t)(t + 1) * 64;
      const size_t kb = bbase + (size_t)(t + 1) * 64;
      a0 = *(const uint4*)(A + ka);  a1 = *(const uint4*)(A + ka + 8);
      b0 = *(const uint4*)(B + kb);  b1 = *(const uint4*)(B + kb + 8);
    }
    #pragma unroll
    for (int ks = 0; ks < 2; ++ks) {
      const bf16x8 af0 = *(const bf16x8*)&As[(wm + fr) * LDP + ks * 32 + fk];
      const bf16x8 af1 = *(const bf16x8*)&As[(wm + 16 + fr) * LDP + ks * 32 + fk];
      const bf16x8 bg0 = *(const bf16x8*)&Bs[(wn + fr) * LDP + ks * 32 + fk];
      const bf16x8 bg1 = *(const bf16x8*)&Bs[(wn + 16 + fr) * LDP + ks * 32 + fk];
      acc[0][0] = __builtin_amdgcn_mfma_f32_16x16x32_bf16(af0, bg0, acc[0][0], 0, 0, 0);
      acc[0][1] = __builtin_amdgcn_mfma_f32_16x16x32_bf16(af0, bg1, acc[0][1], 0, 0, 0);
      acc[1][0] = __builtin_amdgcn_mfma_f32_16x16x32_bf16(af1, bg0, acc[1][0], 0, 0, 0);
      acc[1][1] = __builtin_amdgcn_mfma_f32_16x16x32_bf16(af1, bg1, acc[1][1], 0, 0, 0);
    }
  }
  const long long cb = sC * bz;
  #pragma unroll
  for (int fi = 0; fi < 2; ++fi) {
    #pragma unroll
    for (int r = 0; r < 4; ++r) {
      const int m = m0 + wm + fi * 16 + (lane >> 4) * 4 + r;   // C/D row (m89-verified)
      float rb = 0.f;
      if (BIAS == 2) rb = bias[(size_t)sBias * bz + m];
      #pragma unroll
      for (int fj = 0; fj < 2; ++fj) {
        const int n = n0 + wn + fj * 16 + fr;                  // C/D col = lane&15
        float val = acc[fi][fj][r];
        if (BIAS == 1) val += bscale * bias[n];
        if (BIAS == 2) val += rb;
        if (RELU) val = fmaxf(val, 0.f);
        if (OUTBF) ((unsigned short*)Cv)[cb + (size_t)m * ldc + n] = f2bf(val);
        else       ((float*)Cv)[cb + (size_t)m * ldc + n] = val;
      }
    }
  }
}

// ---------- row softmax (masked) + Kc = exp(10*(S-1)) compacted only ----------
__global__ __launch_bounds__(256) void softmax_kernel(
    const float* __restrict__ QK, const int* __restrict__ Ms,
    const int* __restrict__ pos, float* __restrict__ Kc)
{
  const int r = blockIdx.x;          // 0..2047 (b*128+t)
  const int b = r >> 7;
  const int tid = threadIdx.x;
  const float4 x = *(const float4*)(QK + (size_t)r * HW_DIM + tid * 4);
  const int4 m4 = *(const int4*)(Ms + b * HW_DIM + tid * 4);
  float mx = -3.0e38f;
  if (m4.x) mx = x.x;
  if (m4.y) mx = fmaxf(mx, x.y);
  if (m4.z) mx = fmaxf(mx, x.z);
  if (m4.w) mx = fmaxf(mx, x.w);
  #pragma unroll
  for (int o = 32; o; o >>= 1) mx = fmaxf(mx, __shfl_xor(mx, o));
  __shared__ float red[4];
  const int lane = tid & 63, w = tid >> 6;
  if (lane == 0) red[w] = mx;
  __syncthreads();
  const float gmax = fmaxf(fmaxf(red[0], red[1]), fmaxf(red[2], red[3]));
  __syncthreads();
  const float e0 = m4.x ? __expf(x.x - gmax) : 0.f;
  const float e1 = m4.y ? __expf(x.y - gmax) : 0.f;
  const float e2 = m4.z ? __expf(x.z - gmax) : 0.f;
  const float e3 = m4.w ? __expf(x.w - gmax) : 0.f;
  float s = e0 + e1 + e2 + e3;
  #pragma unroll
  for (int o = 32; o; o >>= 1) s += __shfl_xor(s, o);
  if (lane == 0) red[w] = s;
  __syncthreads();
  const float inv = 1.0f / (red[0] + red[1] + red[2] + red[3]);
  const int4 p4 = *(const int4*)(pos + b * HW_DIM + tid * 4);
  const float ev[4] = {e0, e1, e2, e3};
  const int pp[4] = {p4.x, p4.y, p4.z, p4.w};
  const float* __restrict__ dummy = QK;  // keep signature simple
  (void)dummy;
  #pragma unroll
  for (int q = 0; q < 4; q++)
    if (pp[q] >= 0) Kc[(size_t)r * HW_DIM + pp[q]] = __expf(fmaf(10.f, ev[q] * inv, -10.f));
}

// ---------- Sinkhorn: identical to the round-5 PASS version ----------
__global__ __launch_bounds__(1024, 4) void sinkhorn_kernel(
    const float* __restrict__ Kc, const int* __restrict__ nfg_arr,
    const int* __restrict__ pos, const int* __restrict__ maxIter,
    float* __restrict__ u_out, float* __restrict__ v_out)
{
  const int b = blockIdx.x;
  const int tid = threadIdx.x;
  const int tg = tid >> 6, kg = tid & 63;
  const int nfg = nfg_arr[b];
  const float inv_nfg = 1.0f / (float)nfg;
  const int niter = *maxIter;
  const int njall = (nfg + 63) >> 6;
  __shared__ float part[16][PARTC];
  __shared__ float v_s[HW_DIM];
  __shared__ float u_s[T_DIM];
  __shared__ int conv;
  const float* KB = Kc + (size_t)(b * T_DIM) * HW_DIM;

  if (njall * 64 <= PARTC) {
    const int njr = (njall < NJR) ? njall : NJR;
    float kreg[8][NJR];
    #pragma unroll
    for (int j = 0; j < NJR; j++) {
      #pragma unroll
      for (int i = 0; i < 8; i++) {
        const int col = kg + 64 * j;
        float vle = 0.f;
        if (j < njr && col < nfg) vle = KB[(size_t)(tg * 8 + i) * HW_DIM + col];
        kreg[i][j] = vle;
      }
    }
    if (tid < T_DIM) u_s[tid] = 1.0f / 128.0f;
    if (tid == 0) conv = 1;
    const float bv = (tid < nfg) ? inv_nfg : 0.f;
    float u_prev = 1.0f / 128.0f;
    __syncthreads();

    for (int it = 0; it < niter; ++it) {
      float uu[8];
      #pragma unroll
      for (int i = 0; i < 8; i++) uu[i] = u_s[tg * 8 + i];
      #pragma unroll
      for (int j = 0; j < NJR; j++) {
        if (j < njr) {
          float s = 0.f;
          #pragma unroll
          for (int i = 0; i < 8; i++) s = fmaf(kreg[i][j], uu[i], s);
          part[tg][kg + 64 * j] = s;
        }
      }
      for (int j = NJR; j < njall; ++j) {
        const int col = kg + 64 * j;
        float s = 0.f;
        #pragma unroll
        for (int i = 0; i < 8; i++) {
          const float kk = (col < nfg) ? KB[(size_t)(tg * 8 + i) * HW_DIM + col] : 0.f;
          s = fmaf(kk, uu[i], s);
        }
        part[tg][col] = s;
      }
      __syncthreads();                                        // B1
      if (it != 0 && (it % CHK) == 0) {
        if (conv) break;
      }
      const int checknow = ((it % CHK) == (CHK - 1));
      if (checknow && tid == 0) conv = 1;
      {
        float vv = 0.f;
        if (tid < nfg) {
          float s = 0.f;
          #pragma unroll
          for (int g = 0; g < 16; g++) s += part[g][tid];
          vv = bv * fast_rcp(s);
        }
        v_s[tid] = vv;
      }
      __syncthreads();                                        // B2
      float vload[NJR];
      #pragma unroll
      for (int j = 0; j < NJR; j++) vload[j] = (j < njr) ? v_s[kg + 64 * j] : 0.f;
      float kv[8];
      #pragma unroll
      for (int i = 0; i < 8; i++) {
        float s = 0.f;
        #pragma unroll
        for (int j = 0; j < NJR; j++) s = fmaf(kreg[i][j], vload[j], s);
        kv[i] = s;
      }
      for (int j = NJR; j < njall; ++j) {
        const int col = kg + 64 * j;
        const float vv = v_s[col];
        #pragma unroll
        for (int i = 0; i < 8; i++) {
          const float kk = (col < nfg) ? KB[(size_t)(tg * 8 + i) * HW_DIM + col] : 0.f;
          kv[i] = fmaf(kk, vv, kv[i]);
        }
      }
      float k2[4];
      #pragma unroll
      for (int p = 0; p < 4; p++) {
        const float g = (kg & 1) ? kv[2 * p] : kv[2 * p + 1];
        const float r = __shfl_xor(g, 1);
        k2[p] = ((kg & 1) ? kv[2 * p + 1] : kv[2 * p]) + r;
      }
      float k3[2];
      #pragma unroll
      for (int q = 0; q < 2; q++) {
        const float g = (kg & 2) ? k2[2 * q] : k2[2 * q + 1];
        const float r = __shfl_xor(g, 2);
        k3[q] = ((kg & 2) ? k2[2 * q + 1] : k2[2 * q]) + r;
      }
      float t;
      {
        const float g = (kg & 4) ? k3[0] : k3[1];
        const float r = __shfl_xor(g, 4);
        t = ((kg & 4) ? k3[1] : k3[0]) + r;
      }
      t += __shfl_xor(t, 8);
      t += __shfl_xor(t, 16);
      t += __shfl_xor(t, 32);
      const float u_new = 0.0078125f * fast_rcp(t);
      if (kg < 8) u_s[tg * 8 + kg] = u_new;
      if (checknow) {
        const int ok = (fabsf(u_new - u_prev) <= TOL * fabsf(u_new));
        if (!__all(ok) && kg == 0) conv = 0;
      }
      u_prev = u_new;
    }
    __syncthreads();
    if (tid < T_DIM) u_out[b * T_DIM + tid] = u_s[tid];
    {
      const int p = pos[b * HW_DIM + tid];
      v_out[b * HW_DIM + tid] = (p >= 0) ? v_s[p] : 0.f;
    }
  } else {
    if (tid < T_DIM) u_s[tid] = 1.0f / 128.0f;
    const float bv = (tid < nfg) ? inv_nfg : 0.f;
    __syncthreads();
    for (int it = 0; it < niter; ++it) {
      float vv = 0.f;
      if (tid < nfg) {
        float s = 0.f;
        for (int t = 0; t < T_DIM; t++) s = fmaf(KB[(size_t)t * HW_DIM + tid], u_s[t], s);
        vv = bv * fast_rcp(s);
      }
      v_s[tid] = vv;
      __syncthreads();
      #pragma unroll
      for (int r8 = 0; r8 < 8; r8++) {
        const int r = tg * 8 + r8;
        float s = 0.f;
        for (int j = 0; j < 16; j++) {
          const int col = kg + 64 * j;
          if (col < nfg) s = fmaf(KB[(size_t)r * HW_DIM + col], v_s[col], s);
        }
        #pragma unroll
        for (int o = 32; o; o >>= 1) s += __shfl_xor(s, o);
        if (kg == 0) u_s[r] = 0.0078125f * fast_rcp(s);
      }
      __syncthreads();
    }
    if (tid < T_DIM) u_out[b * T_DIM + tid] = u_s[tid];
    const int p = pos[b * HW_DIM + tid];
    v_out[b * HW_DIM + tid] = (p >= 0) ? v_s[p] : 0.f;
  }
}

// ---------- S_hat = u * Km * v  (Km gathered from compacted Kc), bf16 out ----------
__global__ __launch_bounds__(256) void shat_kernel(const float* __restrict__ Kc,
    const int* __restrict__ pos, const float* __restrict__ u, const float* __restrict__ v,
    unsigned short* __restrict__ Sh)
{
  const int r = blockIdx.x, b = r >> 7, tid = threadIdx.x;
  const float uu = u[r];
  const int4 p4 = *(const int4*)(pos + b * HW_DIM + tid * 4);
  const float4 vv = *(const float4*)(v + (size_t)b * HW_DIM + tid * 4);
  const float* kr = Kc + (size_t)r * HW_DIM;
  const float o0 = (p4.x >= 0) ? uu * kr[p4.x] * vv.x : 0.f;
  const float o1 = (p4.y >= 0) ? uu * kr[p4.y] * vv.y : 0.f;
  const float o2 = (p4.z >= 0) ? uu * kr[p4.z] * vv.z : 0.f;
  const float o3 = (p4.w >= 0) ? uu * kr[p4.w] * vv.w : 0.f;
  uint2 pk;
  pk.x = (unsigned)f2bf(o0) | ((unsigned)f2bf(o1) << 16);
  pk.y = (unsigned)f2bf(o2) | ((unsigned)f2bf(o3) << 16);
  *(uint2*)(Sh + (size_t)r * HW_DIM + tid * 4) = pk;
}

extern "C" void kernel_launch(void* const* d_in, const int* in_sizes, int n_in,
                              void* d_out, int out_size, void* d_ws, size_t ws_size,
                              hipStream_t stream)
{
  const float* F_a  = (const float*)d_in[0];
  const float* F_s  = (const float*)d_in[1];
  const int*   M_s  = (const int*)  d_in[2];
  const float* W_aQ = (const float*)d_in[3];
  const float* b_aQ = (const float*)d_in[4];
  const float* W_sK = (const float*)d_in[5];
  const float* b_sK = (const float*)d_in[6];
  const float* W_sV = (const float*)d_in[7];
  const float* b_sV = (const float*)d_in[8];
  const float* W1   = (const float*)d_in[9];
  const float* b1   = (const float*)d_in[10];
  const float* W2   = (const float*)d_in[11];
  const float* b2   = (const float*)d_in[12];
  const int* maxIter = (const int*)d_in[13];
  float* out = (float*)d_out;

  // ---- fp32 workspace ----
  float* f = (float*)d_ws;
  float* w0 = f;  f += 256;
  float* wq = f;  f += 256;
  float* s0 = f;  f += 4;
  float* qb = f;  f += 2048;
  float* u  = f;  f += 2048;
  float* v  = f;  f += 16 * 1024;
  int* nfg  = (int*)f;  f += 16;
  int* pos  = (int*)f;  f += 16 * 1024;
  float* QK = f;  f += 2048 * 1024;   // 8 MB region (reused: Sh_h + F_a_h)
  float* Kc = f;  f += 2048 * 1024;   // 8 MB region (reused: P_h, then A2/o1/hh)
  // ---- persistent bf16 (ushort) workspace ----
  unsigned short* us = (unsigned short*)f;
  unsigned short* W_sK_h  = us;  us += 256 * 1024;
  unsigned short* W_aQ_h  = us;  us += 256 * 1024;
  unsigned short* F_s_h   = us;  us += 16 * 1024 * 256;
  unsigned short* F_sT_h  = us;  us += 16 * 256 * 1024;
  unsigned short* MmT_h   = us;  us += 256 * 256;
  unsigned short* W_sVT_h = us;  us += 256 * 256;
  unsigned short* W1T_h   = us;  us += 768 * 256;
  unsigned short* W2T_h   = us;  us += 256 * 768;
  // ---- aliased bf16 buffers (into dead fp32 regions; ordering audited) ----
  unsigned short* Sh_h  = (unsigned short*)QK;                 // live: shat -> A2 gemm
  unsigned short* F_a_h = (unsigned short*)QK + 2048 * 1024;   // live: cvt -> P gemm (dead before QK write)
  unsigned short* P_h   = (unsigned short*)Kc;                 // live: P gemm -> QK gemm (dead before softmax)
  unsigned short* A2_h  = (unsigned short*)Kc;                 // live: A2 gemm -> o1 gemm (after Kc dead)
  unsigned short* o1_h  = A2_h + 2048 * 256;
  unsigned short* hh_h  = o1_h + 2048 * 256;

  // mask prep + fp32 bias folds
  prep_kernel<<<16, 256, 0, stream>>>(M_s, nfg, pos);
  wvec_kernel<<<129, 256, 0, stream>>>(W_aQ, b_aQ, W_sK, b_sK, w0, wq, s0);
  qb_kernel<<<512, 256, 0, stream>>>(F_a, wq, s0, qb);

  // bf16 conversions
  cvt_kernel<<<256, 256, 0, stream>>>(F_a, F_a_h, 2048 * 256 / 8);
  cvt_kernel<<<128, 256, 0, stream>>>(W_sK, W_sK_h, 256 * 1024 / 8);
  cvt_kernel<<<128, 256, 0, stream>>>(W_aQ, W_aQ_h, 256 * 1024 / 8);
  cvt_kernel<<<2048, 256, 0, stream>>>(F_s, F_s_h, 16 * 1024 * 256 / 8);
  cvtT_kernel<<<dim3(8, 8, 1),  256, 0, stream>>>(W_sV, 256, 256, 0, W_sVT_h, 0);
  cvtT_kernel<<<dim3(24, 8, 1), 256, 0, stream>>>(W1, 256, 768, 0, W1T_h, 0);
  cvtT_kernel<<<dim3(8, 24, 1), 256, 0, stream>>>(W2, 768, 256, 0, W2T_h, 0);
  cvtT_kernel<<<dim3(8, 32, 16), 256, 0, stream>>>(F_s, 1024, 256, 1024 * 256, F_sT_h, 256 * 1024);

  // MmT = W_sK x W_aQ^T   [256,256] K=1024  (MmT = (W_aQ @ W_sK^T)^T)
  mgemm_kernel<0,false,true><<<dim3(4,4,1),256,0,stream>>>(W_sK_h,1024,0, W_aQ_h,1024,0, MmT_h,256,0, 1024, nullptr,0,0.f);
  // P = F_a x MmT^T + w0   [2048,256] K=256
  mgemm_kernel<1,false,true><<<dim3(4,32,1),256,0,stream>>>(F_a_h,256,0, MmT_h,256,0, P_h,256,0, 256, w0,0,1.0f);
  // QK[b] = P[b] x F_s[b]^T + qb  [128,1024] K=256  (fp32 out)
  mgemm_kernel<2,false,false><<<dim3(16,2,16),256,0,stream>>>(P_h,256,128*256, F_s_h,256,1024*256, QK,1024,128LL*1024, 256, qb,128,0.f);

  softmax_kernel<<<2048, 256, 0, stream>>>(QK, M_s, pos, Kc);
  sinkhorn_kernel<<<16, 1024, 0, stream>>>(Kc, nfg, pos, maxIter, u, v);
  shat_kernel<<<2048, 256, 0, stream>>>(Kc, pos, u, v, Sh_h);

  // A2[b] = Sh[b] x F_sT[b]^T   [128,256] K=1024  (bf16 out)
  mgemm_kernel<0,false,true><<<dim3(4,2,16),256,0,stream>>>(Sh_h,1024,128*1024, F_sT_h,1024,256*1024, A2_h,256,128LL*256, 1024, nullptr,0,0.f);
  // o1 = A2 x W_sVT^T + (1/T) b_sV   [2048,256] K=256
  mgemm_kernel<1,false,true><<<dim3(4,32,1),256,0,stream>>>(A2_h,256,0, W_sVT_h,256,0, o1_h,256,0, 256, b_sV,0,0.0078125f);
  // hh = relu(o1 x W1T^T + b1)   [2048,768] K=256
  mgemm_kernel<1,true,true><<<dim3(12,32,1),256,0,stream>>>(o1_h,256,0, W1T_h,256,0, hh_h,768,0, 256, b1,0,1.0f);
  // out = hh x W2T^T + b2   [2048,256] K=768  (fp32 out)
  mgemm_kernel<1,false,false><<<dim3(4,32,1),256,0,stream>>>(hh_h,768,0, W2T_h,768,0, out,256,0, 768, b2,0,1.0f);
}